// Round 5
// baseline (453.259 us; speedup 1.0000x reference)
//
#include <hip/hip_runtime.h>
#include <cstdint>
#include <cstddef>

// Problem dims (fixed by the reference: B=8, S=2048, DIN=1152, DOUT=4608)
#define M_DIM 16384   // B*S
#define N_DIM 4608    // DOUT
#define K_DIM 1152    // DIN
#define NKT64 (K_DIM / 64)   // 18 K-tiles of 64 int8 bytes

typedef __attribute__((ext_vector_type(8))) __bf16 bf16x8;
typedef __attribute__((ext_vector_type(4))) float  f32x4;
typedef __attribute__((ext_vector_type(4))) int    v4i;

__device__ __forceinline__ unsigned short f2bf(float f) {
    unsigned int u = __float_as_uint(f);
    unsigned int r = (u + 0x7FFFu + ((u >> 16) & 1u)) >> 16;
    return (unsigned short)r;
}

__device__ __forceinline__ float gelu_tanh_f(float v) {
    // 0.5*v*(1+tanh(u)) == v * sigmoid(2u), u = c0*(v + c1*v^3)
    // 2u = v*(2*c0 + 2*c0*c1*v^2). Algebraically identical to the tanh form.
    // NaN-free for finite v: e in [0,inf], v/(1+e) well-defined (0 at -inf).
    float v2 = v * v;
    float u2 = v * fmaf(v2, 0.07135481627260093f, 1.5957691216057308f);
    float e  = __expf(-u2);
    return v / (1.0f + e);
}

// ---------------- merged prepass ----------------
// Blocks [0, M_DIM/4): per-row dynamic int8 quantization of A (1 wave/row).
// Blocks [M_DIM/4, ...): pack int32 weights -> int8 (exact).
#define QA_BLOCKS (M_DIM / 4)
#define W4_COUNT  ((N_DIM * K_DIM) / 4)
#define PW_BLOCKS ((W4_COUNT + 255) / 256)

__global__ void prepass(const float* __restrict__ A,
                        const int* __restrict__ w,
                        signed char* __restrict__ qa,
                        float* __restrict__ sA,
                        signed char* __restrict__ qw) {
    if (blockIdx.x < QA_BLOCKS) {
        const int lane = threadIdx.x & 63;
        const int row  = blockIdx.x * 4 + (threadIdx.x >> 6);
        const float2* src = (const float2*)(A + (size_t)row * K_DIM);
        float2 v[9];
        float amax = 0.f;
#pragma unroll
        for (int j = 0; j < 9; ++j) {
            v[j] = src[j * 64 + lane];
            amax = fmaxf(amax, fmaxf(fabsf(v[j].x), fabsf(v[j].y)));
        }
#pragma unroll
        for (int off = 32; off > 0; off >>= 1)
            amax = fmaxf(amax, __shfl_xor(amax, off));
        amax = fmaxf(amax, 1e-30f);
        float inv = 127.0f / amax;
        if (lane == 0) sA[row] = amax * (1.0f / 127.0f);
        char2* dst = (char2*)(qa + (size_t)row * K_DIM);
#pragma unroll
        for (int j = 0; j < 9; ++j) {
            char2 o;
            o.x = (signed char)__float2int_rn(v[j].x * inv);
            o.y = (signed char)__float2int_rn(v[j].y * inv);
            dst[j * 64 + lane] = o;
        }
    } else {
        int i = (blockIdx.x - QA_BLOCKS) * 256 + threadIdx.x;
        if (i >= W4_COUNT) return;
        int4 v = ((const int4*)w)[i];
        char4 o;
        o.x = (signed char)v.x; o.y = (signed char)v.y;
        o.z = (signed char)v.z; o.w = (signed char)v.w;
        ((char4*)qw)[i] = o;
    }
}

// ---------------- i8 GEMM, 128x128 tile, occupancy-first ----------------
// Round-4 counters: MfmaUtil 19%, Occupancy 20.7% — 256-reg waves (128 VGPR +
// 128 AGPR acc) = 2 waves/SIMD and 128KB LDS = 1 block/CU: lockstep barriers
// with no foreign waves to hide stalls, 4.5 sequential blocks/CU each paying
// full prologue/drain. Fix: shrink to 64-reg acc (64x64/wave), 32KB LDS,
// __launch_bounds__(256,3) => 3 independent blocks/CU (12 waves, 3/SIMD).
// 2-barrier double-buffered loop with counted vmcnt(4) (m97 recipe: implicit
// cross-block wave overlap does the pipelining — m114).
// LDS rows are 64B = 4x16B chunks, XOR swizzle chunk^=(row&3): linear
// global_load_lds dest + pre-swizzled global source + swizzled ds_read.
// 2-way read aliasing remains (4-chunk swizzle) — free per m136.

__global__ __launch_bounds__(256, 3) void qgemm_i8_128(
    const signed char* __restrict__ Aq,
    const signed char* __restrict__ Wq,
    const float* __restrict__ sA,
    const float* __restrict__ w_scale,
    const float* __restrict__ bias,
    float* __restrict__ out) {
    __shared__ __align__(16) signed char As[2][128 * 64];
    __shared__ __align__(16) signed char Bs[2][128 * 64];

    const int tid    = threadIdx.x;
    const int l      = tid & 63;
    const int wv     = tid >> 6;       // 0..3
    const int lane16 = l & 15;
    const int quad   = l >> 4;

    // XCD-aware swizzle: 4608 blocks = 8 XCDs x 576 (nwg%8==0 -> simple form).
    // Within an XCD chunk, n-tile fastest: A panel (147KB) L2-resident.
    const int bid = blockIdx.x;
    const int swz = (bid & 7) * (4608 / 8) + (bid >> 3);
    const int m0  = (swz / 36) * 128;
    const int n0  = (swz % 36) * 128;

    const int wm = (wv & 1) * 64;
    const int wn = (wv >> 1) * 64;

    // stage one K-tile (A 8KB + B 8KB) = 4 global_load_lds per thread
    auto stage = [&](int buf, int kt) {
#pragma unroll
        for (int j = 0; j < 2; ++j) {
            int q   = j * 256 + tid;          // 16B-chunk idx 0..511
            int row = q >> 2;                 // 0..127
            int c   = (q & 3) ^ (row & 3);    // pre-swizzled global chunk
            const signed char* gA = Aq + (size_t)(m0 + row) * K_DIM + kt * 64 + c * 16;
            const signed char* gB = Wq + (size_t)(n0 + row) * K_DIM + kt * 64 + c * 16;
            // linear LDS dest: per-j wave-uniform base + lane*16
            __builtin_amdgcn_global_load_lds(
                (const __attribute__((address_space(1))) unsigned int*)gA,
                (__attribute__((address_space(3))) unsigned int*)&As[buf][q * 16], 16, 0, 0);
            __builtin_amdgcn_global_load_lds(
                (const __attribute__((address_space(1))) unsigned int*)gB,
                (__attribute__((address_space(3))) unsigned int*)&Bs[buf][q * 16], 16, 0, 0);
        }
    };

    v4i acc[4][4];
#pragma unroll
    for (int i = 0; i < 4; ++i)
#pragma unroll
        for (int j = 0; j < 4; ++j) acc[i][j] = v4i{0, 0, 0, 0};

    // prologue: stage kt=0 into buf0
    stage(0, 0);

    for (int kt = 0; kt < NKT64; ++kt) {
        const int cur = kt & 1;
        if (kt + 1 < NKT64) {
            stage(cur ^ 1, kt + 1);   // issue next-tile loads first
            asm volatile("s_waitcnt vmcnt(4)" ::: "memory");  // kt's 4 done
        } else {
            asm volatile("s_waitcnt vmcnt(0)" ::: "memory");
        }
        __builtin_amdgcn_sched_barrier(0);
        __builtin_amdgcn_s_barrier();   // buf[cur] fully staged (all waves)

        v4i a[4], b[4];
#pragma unroll
        for (int mt = 0; mt < 4; ++mt) {
            int r = wm + mt * 16 + lane16;
            int p = quad ^ (r & 3);
            a[mt] = *(const v4i*)&As[cur][r * 64 + p * 16];
        }
#pragma unroll
        for (int nt = 0; nt < 4; ++nt) {
            int r = wn + nt * 16 + lane16;
            int p = quad ^ (r & 3);
            b[nt] = *(const v4i*)&Bs[cur][r * 64 + p * 16];
        }
        __builtin_amdgcn_s_setprio(1);
#pragma unroll
        for (int mt = 0; mt < 4; ++mt)
#pragma unroll
            for (int nt = 0; nt < 4; ++nt)
                acc[mt][nt] = __builtin_amdgcn_mfma_i32_16x16x64_i8(
                    a[mt], b[nt], acc[mt][nt], 0, 0, 0);
        __builtin_amdgcn_s_setprio(0);
        __builtin_amdgcn_s_barrier();   // reads of buf[cur] done before next
                                        // iter's stage overwrites it
    }

    // ---- hard handoff: all waves' LDS ops drained before scratch reuse ----
    __syncthreads();

    // ---- epilogue: gelu -> per-wave LDS transpose -> 256B-contiguous NT ----
    // Per mt round: wave stages 16 rows x 64 floats (4KB) with 16B-chunk XOR
    // swizzle (chunk ^= row16), reads back ds_read_b128, stores dwordx4:
    // 16 lanes x 16B = 256B contiguous per row (verified round 4, −16 us).
    float sc4[4], bi4[4];
#pragma unroll
    for (int nt = 0; nt < 4; ++nt) {
        int n = n0 + wn + nt * 16 + lane16;
        sc4[nt] = w_scale[n];
        bi4[nt] = bias[n];
    }

    float* scr = (float*)(&As[0][0]) + wv * 1024;  // 4KB per wave (16KB of 32)
    const int lo3 = lane16 & 3;

#pragma unroll
    for (int mt = 0; mt < 4; ++mt) {
        const int rbase = m0 + wm + mt * 16;       // global m of row16==0
        const f32x4 sa = *(const f32x4*)(sA + rbase + quad * 4);
#pragma unroll
        for (int nt = 0; nt < 4; ++nt) {
            const int col   = nt * 16 + lane16;    // 0..63
            const int chunk = col >> 2;            // 0..15
#pragma unroll
            for (int r = 0; r < 4; ++r) {
                const int row16 = quad * 4 + r;
                const int c2    = chunk ^ row16;
                float v = (float)acc[mt][nt][r] * sa[r] * sc4[nt] + bi4[nt];
                scr[row16 * 64 + c2 * 4 + lo3] = gelu_tanh_f(v);
            }
        }
        // writes visible before cross-lane readback (same-wave ds ordering)
        asm volatile("s_waitcnt lgkmcnt(0)" ::: "memory");
        __builtin_amdgcn_sched_barrier(0);
#pragma unroll
        for (int s = 0; s < 4; ++s) {
            const int row16 = s * 4 + quad;
            const int c2    = lane16 ^ row16;      // logical chunk == lane16
            f32x4 val = *(const f32x4*)(scr + row16 * 64 + c2 * 4);
            __builtin_nontemporal_store(
                val, (f32x4*)(out + (size_t)(rbase + row16) * N_DIM
                              + n0 + wn + lane16 * 4));
        }
        // reads land in VGPRs before next round overwrites the scratch
        asm volatile("s_waitcnt lgkmcnt(0)" ::: "memory");
        __builtin_amdgcn_sched_barrier(0);
    }
}

// ---------------- bf16 fused fallback (if ws too small) --------------------
__global__ void qgelu_gemm_bf16_fused(const float* __restrict__ Af,
                                      const int* __restrict__ Wi,
                                      const float* __restrict__ w_scale,
                                      const float* __restrict__ bias,
                                      float* __restrict__ out) {
    __shared__ __align__(16) unsigned short As[128 * 64];
    __shared__ __align__(16) unsigned short Bs[128 * 64];

    const int tid    = threadIdx.x;
    const int l      = tid & 63;
    const int wv     = tid >> 6;
    const int lane16 = l & 15;
    const int quad   = l >> 4;
    const int m0 = blockIdx.x * 128;
    const int n0 = blockIdx.y * 128;
    const int wm = (wv & 1) * 64;
    const int wn = (wv >> 1) * 64;

    f32x4 acc[4][4];
#pragma unroll
    for (int i = 0; i < 4; ++i)
#pragma unroll
        for (int j = 0; j < 4; ++j) acc[i][j] = f32x4{0.f, 0.f, 0.f, 0.f};

    for (int kt = 0; kt < K_DIM / 64; ++kt) {
        __syncthreads();
#pragma unroll
        for (int i = 0; i < 8; ++i) {
            int g    = i * 256 + tid;
            int row  = g >> 4;
            int grp  = g & 15;
            int c    = grp >> 1;
            int half = g & 1;
            int p    = c ^ (row & 7);
            int off  = row * 64 + p * 8 + half * 4;
            {
                float4 v = *(const float4*)(Af + (size_t)(m0 + row) * K_DIM + kt * 64 + grp * 4);
                ushort4 o;
                o.x = f2bf(v.x); o.y = f2bf(v.y); o.z = f2bf(v.z); o.w = f2bf(v.w);
                *(ushort4*)(As + off) = o;
            }
            {
                int4 v = *(const int4*)(Wi + (size_t)(n0 + row) * K_DIM + kt * 64 + grp * 4);
                ushort4 o;
                o.x = f2bf((float)v.x); o.y = f2bf((float)v.y);
                o.z = f2bf((float)v.z); o.w = f2bf((float)v.w);
                *(ushort4*)(Bs + off) = o;
            }
        }
        __syncthreads();

#pragma unroll
        for (int s = 0; s < 2; ++s) {
            bf16x8 af[4], bfr[4];
#pragma unroll
            for (int mt = 0; mt < 4; ++mt) {
                int row = wm + mt * 16 + lane16;
                int p   = (s * 4 + quad) ^ (row & 7);
                af[mt]  = *(const bf16x8*)(As + row * 64 + p * 8);
            }
#pragma unroll
            for (int nt = 0; nt < 4; ++nt) {
                int row = wn + nt * 16 + lane16;
                int p   = (s * 4 + quad) ^ (row & 7);
                bfr[nt] = *(const bf16x8*)(Bs + row * 64 + p * 8);
            }
#pragma unroll
            for (int mt = 0; mt < 4; ++mt)
#pragma unroll
                for (int nt = 0; nt < 4; ++nt)
                    acc[mt][nt] = __builtin_amdgcn_mfma_f32_16x16x32_bf16(
                        af[mt], bfr[nt], acc[mt][nt], 0, 0, 0);
        }
    }

#pragma unroll
    for (int nt = 0; nt < 4; ++nt) {
        int n    = n0 + wn + nt * 16 + lane16;
        float sc = w_scale[n];
        float bi = bias[n];
#pragma unroll
        for (int mt = 0; mt < 4; ++mt) {
#pragma unroll
            for (int r = 0; r < 4; ++r) {
                int m   = m0 + wm + mt * 16 + quad * 4 + r;
                float v = acc[mt][nt][r] * sc + bi;
                __builtin_nontemporal_store(
                    gelu_tanh_f(v), &out[(size_t)m * N_DIM + n]);
            }
        }
    }
}

extern "C" void kernel_launch(void* const* d_in, const int* in_sizes, int n_in,
                              void* d_out, int out_size, void* d_ws, size_t ws_size,
                              hipStream_t stream) {
    const float* hs   = (const float*)d_in[0];  // [8,2048,1152] fp32
    const int*   w8   = (const int*)d_in[1];    // [4608,1152] int32 (int8 values)
    const float* wsc  = (const float*)d_in[2];  // [4608]
    const float* bias = (const float*)d_in[3];  // [4608]
    float* out = (float*)d_out;                 // [8,2048,4608] fp32

    const size_t nA = (size_t)M_DIM * K_DIM;  // int8 elems
    const size_t nW = (size_t)N_DIM * K_DIM;
    const size_t need = nA + nW + (size_t)M_DIM * sizeof(float);

    if (ws_size >= need) {
        signed char* qa = (signed char*)d_ws;
        signed char* qw = qa + nA;
        float* sA = (float*)(qa + nA + nW);  // 16B-aligned (nA+nW % 16 == 0)
        prepass<<<QA_BLOCKS + PW_BLOCKS, 256, 0, stream>>>(hs, w8, qa, sA, qw);
        qgemm_i8_128<<<dim3((M_DIM / 128) * (N_DIM / 128)), 256, 0, stream>>>(
            qa, qw, sA, wsc, bias, out);
    } else {
        dim3 grid(M_DIM / 128, N_DIM / 128);
        qgelu_gemm_bf16_fused<<<grid, 256, 0, stream>>>(hs, w8, wsc, bias, out);
    }
}